// Round 1
// baseline (3265.828 us; speedup 1.0000x reference)
//
#include <hip/hip_runtime.h>
#include <cstdint>
#include <cstddef>

// Problem constants (match reference)
#define NIT    500
#define GAMMA_ 5.0f
#define CC_    1e-3f
#define KAPPA_ 2.0627128075074256f
#define PEN_   100.0f
#define LR_    0.01f

// d_ws layout: pbuf [128 b][2 half][2 parity][100] f32 = 204800 B, then flags [256] int = 1024 B
#define PBUF_BYTES 204800
#define FLAG_BYTES 1024

__device__ __forceinline__ float wred64(float x) {
#pragma unroll
  for (int m = 1; m < 64; m <<= 1) x += __shfl_xor(x, m, 64);
  return x;
}
__device__ __forceinline__ float rdlane(float v, int lane) {
  return __int_as_float(__builtin_amdgcn_readlane(__float_as_int(v), lane));
}

// One WG per (b, half): 6 heads, 12 waves (2 waves/head). S rows live in VGPRs.
__global__ __launch_bounds__(768, 3) void mpo_solver(
    const float* __restrict__ mu, const float* __restrict__ L,
    const float* __restrict__ wprev, const float* __restrict__ climit,
    float* __restrict__ out, float* __restrict__ pbuf, int* __restrict__ flags)
{
  const int tid  = threadIdx.x;
  const int lane = tid & 63;
  const int wave = tid >> 6;        // 0..11
  const int j    = wave >> 1;       // local head 0..5
  const int sec  = wave & 1;        // 0 = primary (rows 0-49 + post), 1 = secondary (rows 50-99)
  const int bid  = blockIdx.x;
  const int b    = bid & 127;
  const int half = bid >> 7;        // 0: heads 0-5, 1: heads 6-11
  const int h    = half * 6 + j;    // global head
  const int bh   = b * 12 + h;
  const int bhu  = __builtin_amdgcn_readfirstlane(bh);

  __shared__ float wbuf[2][6][100];   // double-buffered w per head
  __shared__ float ybuf[6][100];      // y = S w per head
  __shared__ float part[6][2][2];     // [head][wavehalf][ret, s2]

  const float* Lb = L + (size_t)bhu * 10000;

  // ---------- Phase 0: SYRK. Lane owns row r of S = L L^T (fp32, in registers). ----------
  float S[100];
#pragma unroll
  for (int c = 0; c < 100; ++c) S[c] = 0.f;
  const int r = sec * 50 + lane;      // valid row iff lane < 50
  if (lane < 50) {
#pragma unroll 1
    for (int mc = 0; mc < 25; ++mc) {
      float4 lr = *(const float4*)(Lb + r * 100 + mc * 4);
#pragma unroll
      for (int c = 0; c < 100; ++c) {
        const float* Lc = Lb + c * 100 + mc * 4;   // wave-uniform address -> scalar loads
        S[c] = fmaf(lr.x, Lc[0], fmaf(lr.y, Lc[1], fmaf(lr.z, Lc[2], fmaf(lr.w, Lc[3], S[c]))));
      }
    }
  }

  // per-lane constants
  float mu_m = (lane < 50) ? mu[(size_t)bhu * 100 + r] : 0.f;  // for ret partial over own rows
  float mu0  = mu[(size_t)bhu * 100 + lane];
  float mu1  = (lane < 36) ? mu[(size_t)bhu * 100 + 64 + lane] : 0.f;
  float wp0  = wprev[b * 100 + lane];
  float wp1  = (lane < 36) ? wprev[b * 100 + 64 + lane] : 0.f;
  float lim  = climit[b];

  float w0 = wp0, w1 = wp1;           // primary's current iterate elems (n = lane, lane+64)

  if (sec == 0) {
    wbuf[0][j][lane] = wp0;
    if (lane < 36) wbuf[0][j][64 + lane] = wp1;
  }
  __syncthreads();

  const bool isPubL  = (half == 0) && (j == 5);  // publishes head 5, waits on head 6
  const bool isPubH  = (half == 1) && (j == 0);  // publishes head 6, waits on head 5
  const bool hasNext = (h < 11);
  const int  flagPub = isPubL ? (b * 2 + 0) : (b * 2 + 1);
  bool dead = false;

  for (int k = 0; k < NIT; ++k) {
    const int p = k & 1;
    // ---------- matvec y = S * w_k (all 12 waves) ----------
    float vw0 = wbuf[p][j][lane];
    float vw1 = (lane < 36) ? wbuf[p][j][64 + lane] : 0.f;
    float acc = 0.f;
#pragma unroll
    for (int c = 0; c < 64; ++c)  acc = fmaf(rdlane(vw0, c), S[c], acc);
#pragma unroll
    for (int c = 64; c < 100; ++c) acc = fmaf(rdlane(vw1, c - 64), S[c], acc);
    if (lane < 50) ybuf[j][r] = acc;
    float wm   = (lane < 50) ? wbuf[p][j][r] : 0.f;
    float accz = (lane < 50) ? acc : 0.f;
    float pr = wred64(mu_m * wm);
    float ps = wred64(accz * wm);
    if (lane == 0) { part[j][sec][0] = pr; part[j][sec][1] = ps; }
    __syncthreads();

    // ---------- post phase: primary wave per head ----------
    if (sec == 0) {
      float ret   = part[j][0][0] + part[j][1][0];
      float s2    = part[j][0][1] + part[j][1][1];
      float sigma = sqrtf(s2 + 1e-12f);
      float z     = KAPPA_ * sigma - ret - lim;
      float act   = (z > 0.f) ? 1.f : 0.f;
      float cY    = 2.f * GAMMA_ + act * (PEN_ * KAPPA_ / sigma);
      float cM    = -(1.f + act * PEN_);

      // neighbor w (current iterate)
      float wl0, wl1, wn0 = 0.f, wn1 = 0.f;
      if (j == 0) {
        if (half == 0 || k == 0) { wl0 = wp0; wl1 = wp1; }
        else {
          if (!dead) {
            long guard = 0;
            while (__hip_atomic_load(&flags[b * 2 + 0], __ATOMIC_ACQUIRE, __HIP_MEMORY_SCOPE_AGENT) < k) {
              __builtin_amdgcn_s_sleep(8);
              if (++guard > (1L << 20)) { dead = true; break; }
            }
          }
          float* src = pbuf + ((size_t)(b * 2 + 0) * 2 + (k & 1)) * 100;
          wl0 = __hip_atomic_load(&src[lane], __ATOMIC_RELAXED, __HIP_MEMORY_SCOPE_AGENT);
          wl1 = (lane < 36) ? __hip_atomic_load(&src[64 + lane], __ATOMIC_RELAXED, __HIP_MEMORY_SCOPE_AGENT) : 0.f;
        }
      } else { wl0 = wbuf[p][j - 1][lane]; wl1 = (lane < 36) ? wbuf[p][j - 1][64 + lane] : 0.f; }
      if (hasNext) {
        if (j == 5) {  // half==0 boundary: next is head 6
          if (k == 0) { wn0 = wp0; wn1 = wp1; }
          else {
            if (!dead) {
              long guard = 0;
              while (__hip_atomic_load(&flags[b * 2 + 1], __ATOMIC_ACQUIRE, __HIP_MEMORY_SCOPE_AGENT) < k) {
                __builtin_amdgcn_s_sleep(8);
                if (++guard > (1L << 20)) { dead = true; break; }
              }
            }
            float* src = pbuf + ((size_t)(b * 2 + 1) * 2 + (k & 1)) * 100;
            wn0 = __hip_atomic_load(&src[lane], __ATOMIC_RELAXED, __HIP_MEMORY_SCOPE_AGENT);
            wn1 = (lane < 36) ? __hip_atomic_load(&src[64 + lane], __ATOMIC_RELAXED, __HIP_MEMORY_SCOPE_AGENT) : 0.f;
          }
        } else { wn0 = wbuf[p][j + 1][lane]; wn1 = (lane < 36) ? wbuf[p][j + 1][64 + lane] : 0.f; }
      }

      float y0 = ybuf[j][lane];
      float y1 = (lane < 36) ? ybuf[j][64 + lane] : 0.f;
      const bool val1 = (lane < 36);

      float dw0 = w0 - wl0;
      float g0  = fmaf(cM, mu0, cY * y0) + CC_ * (dw0 * rsqrtf(fmaf(dw0, dw0, 1e-10f)));
      if (hasNext) { float dn0 = wn0 - w0; g0 -= CC_ * (dn0 * rsqrtf(fmaf(dn0, dn0, 1e-10f))); }
      float v0 = fmaf(-LR_, g0, w0);
      float v1 = 0.f;
      if (val1) {
        float dw1 = w1 - wl1;
        float g1  = fmaf(cM, mu1, cY * y1) + CC_ * (dw1 * rsqrtf(fmaf(dw1, dw1, 1e-10f)));
        if (hasNext) { float dn1 = wn1 - w1; g1 -= CC_ * (dn1 * rsqrtf(fmaf(dn1, dn1, 1e-10f))); }
        v1 = fmaf(-LR_, g1, w1);
      }

      // ---- Michelot simplex projection (exact, finite convergence) ----
      float a1    = val1 ? 1.f : 0.f;
      float Ssum  = wred64(v0 + a1 * v1);
      float Cnt   = wred64(1.f + a1);
      float theta = 0.f;
      for (int it = 0; it < 100; ++it) {
        theta = (Ssum - 1.f) / Cnt;
        float na0 = (v0 > theta) ? 1.f : 0.f;
        float na1 = (val1 && (v1 > theta)) ? 1.f : 0.f;
        float ns = wred64(na0 * v0 + na1 * v1);
        float nc = wred64(na0 + na1);
        if (nc == Cnt) break;
        Ssum = ns; Cnt = nc;
      }
      w0 = fmaxf(v0 - theta, 0.f);
      w1 = val1 ? fmaxf(v1 - theta, 0.f) : 0.f;

      wbuf[1 - p][j][lane] = w0;
      if (val1) wbuf[1 - p][j][64 + lane] = w1;

      if (isPubL || isPubH) {
        float* dst = pbuf + ((size_t)flagPub * 2 + ((k + 1) & 1)) * 100;
        __hip_atomic_store(&dst[lane], w0, __ATOMIC_RELAXED, __HIP_MEMORY_SCOPE_AGENT);
        if (val1) __hip_atomic_store(&dst[64 + lane], w1, __ATOMIC_RELAXED, __HIP_MEMORY_SCOPE_AGENT);
        if (lane == 0)
          __hip_atomic_store(&flags[flagPub], k + 1, __ATOMIC_RELEASE, __HIP_MEMORY_SCOPE_AGENT);
      }
    }
    __syncthreads();
  }

  if (sec == 0) {
    float* o = out + (size_t)bhu * 100;
    o[lane] = w0;
    if (lane < 36) o[64 + lane] = w1;
  }
}

extern "C" void kernel_launch(void* const* d_in, const int* in_sizes, int n_in,
                              void* d_out, int out_size, void* d_ws, size_t ws_size,
                              hipStream_t stream) {
  const float* mu = (const float*)d_in[0];
  const float* L  = (const float*)d_in[1];
  const float* wp = (const float*)d_in[2];
  const float* cl = (const float*)d_in[3];
  float* pbuf = (float*)d_ws;
  int*   flags = (int*)((char*)d_ws + PBUF_BYTES);
  // flags must be zeroed every launch (ws is re-poisoned 0xAA before timed replays)
  hipMemsetAsync(flags, 0, FLAG_BYTES, stream);
  hipLaunchKernelGGL(mpo_solver, dim3(256), dim3(768), 0, stream,
                     mu, L, wp, cl, (float*)d_out, pbuf, flags);
}